// Round 8
// baseline (139.847 us; speedup 1.0000x reference)
//
#include <hip/hip_runtime.h>
#include <hip/hip_bf16.h>

typedef __attribute__((ext_vector_type(8))) __bf16 bf16x8;
typedef __attribute__((ext_vector_type(16))) float f32x16;

#if __has_builtin(__builtin_amdgcn_exp2f)
#define EXP2F(x) __builtin_amdgcn_exp2f(x)
#else
#define EXP2F(x) exp2f(x)
#endif

static constexpr int BB = 8, CC = 64, NN = 4096;
// ws layout (bytes): qfrag[1MB] | kfrag[2MB @2MB] | vfrag[4MB @4MB]
static constexpr size_t QF_OFF = 0;
static constexpr size_t KF_OFF = (size_t)2 << 20;
static constexpr size_t VF_OFF = (size_t)4 << 20;

// 32x32x16 fragment arrays (bf16). Operand layouts (gfx950):
//   A[m=lane&31][k=(lane>>5)*8+r]  B[k=(lane>>5)*8+r][n=lane&31]
//   C/D: col(n)=lane&31, row(m)=(reg&3)+8*(reg>>2)+4*(lane>>5), reg in [0,16)
// qfrag[b][it32(128)][lane][8] : i = it32*32+(lane&31); hB=lane>>5:
//     hB=0 -> qhi[r], hB=1 -> qlo[r]   (q pre-scaled by log2e, +bias)
// kfrag[b][jt(128)][2][lane][8] : j = jt*32 + (lane&31)
//     frag0 (A1): k8[r] = khi[r] (both halves)  -> pairs with qhi|qlo
//     frag1 (A2): hA=0 -> klo[r], hA=1 -> 0     -> pairs with qhi only
//   -> energy = khi*qhi + khi*qlo + klo*qhi  (klo*qlo ~2^-18, dropped)
// vfrag[b][jt(128)][ct(2)][jh(2)][lane][8] : c = ct*32+(lane&31);
//     slot r -> j = jt*32 + jh*16 + 4*(lane>>5) + 8*(r>>2) + (r&3)
//     (j-permutation == energy C/D row order per k-half, so exp() results ARE
//      the PV B-operand: p1 = e-regs 0-7 with vfrag jh=0, p2 = regs 8-15 / jh=1)

__global__ __launch_bounds__(512) void proj_kernel(
    const float* __restrict__ query, const float* __restrict__ value,
    const float* __restrict__ Wq, const float* __restrict__ bq,
    const float* __restrict__ Wk, const float* __restrict__ bk,
    const float* __restrict__ Wv, const float* __restrict__ bv,
    char* __restrict__ ws) {
  __shared__ float qs[64][64];      // staged q-tile [c][px]
  __shared__ float vvs[64][64];     // staged v-tile [c][px]
  __shared__ __bf16 vlds[64][72];   // [px][c], padded row
  __shared__ float  qlds[64][9];    // [px][o], log2e-scaled, +bias
  __shared__ float  klds[64][9];
  const float LOG2E = 1.4426950408889634f;
  int t = threadIdx.x;
  int part = __builtin_amdgcn_readfirstlane(t >> 6);   // 0..7, wave-uniform
  int px = t & 63;
  int blk = blockIdx.x;
  int b = blk >> 6;
  int px0 = (blk & 63) << 6;        // 64 pixels per block
  size_t inbase = (size_t)b * CC * NN + px0 + px;

  // cooperative stage: each part loads ITS 8 channels once (coalesced)
  #pragma unroll
  for (int cc = 0; cc < 8; ++cc) {
    int c = part * 8 + cc;
    qs[c][px]  = query[inbase + (size_t)c * NN];
    vvs[c][px] = value[inbase + (size_t)c * NN];
  }
  __syncthreads();

  bool isq = part < 4;              // parts 0-3 -> q rows, 4-7 -> k rows
  int qko = (part & 3) * 2;         // two qk output rows per part
  const float* __restrict__ Wqk = isq ? Wq : Wk;

  float vacc[8];
  #pragma unroll
  for (int o = 0; o < 8; ++o) vacc[o] = bv[part * 8 + o];
  float qk0 = 0.f, qk1 = 0.f;

  #pragma unroll
  for (int cb = 0; cb < 4; ++cb) {
    float xq[16], xv[16];
    #pragma unroll
    for (int cc = 0; cc < 16; ++cc) {
      xq[cc] = qs[cb * 16 + cc][px];
      xv[cc] = vvs[cb * 16 + cc][px];
    }
    #pragma unroll
    for (int cc = 0; cc < 16; ++cc) {
      int c = cb * 16 + cc;
      qk0 += Wqk[qko * 64 + c] * xq[cc];
      qk1 += Wqk[(qko + 1) * 64 + c] * xq[cc];
      #pragma unroll
      for (int o = 0; o < 8; ++o) vacc[o] += Wv[(part * 8 + o) * 64 + c] * xv[cc];
    }
  }

  #pragma unroll
  for (int o = 0; o < 8; ++o) vlds[px][part * 8 + o] = (__bf16)vacc[o];
  if (isq) {
    qlds[px][qko]     = (qk0 + bq[qko]) * LOG2E;
    qlds[px][qko + 1] = (qk1 + bq[qko + 1]) * LOG2E;
  } else {
    klds[px][qko]     = qk0 + bk[qko];
    klds[px][qko + 1] = qk1 + bk[qko + 1];
  }
  __syncthreads();

  // ---- fragment building (32x32 layouts documented above)
  __bf16* qfrag = (__bf16*)(ws + QF_OFF);
  __bf16* kfrag = (__bf16*)(ws + KF_OFF);
  __bf16* vfrag = (__bf16*)(ws + VF_OFF);
  int l = t & 63, il = l & 31, hA = l >> 5;
  int w = t >> 6;

  {  // vfrag: wave w -> (jt = w>>2, ct = (w>>1)&1, jh = w&1); one store each
    int jt = w >> 2, ct = (w >> 1) & 1, jh = w & 1;
    bf16x8 v8;
    #pragma unroll
    for (int r = 0; r < 8; ++r) {
      int jj = jt * 32 + jh * 16 + 4 * hA + 8 * (r >> 2) + (r & 3);
      v8[r] = vlds[jj][ct * 32 + il];
    }
    int jtg = (blk & 63) * 2 + jt;
    *(bf16x8*)(vfrag + (((((size_t)b * 128 + jtg) * 2 + ct) * 2 + jh) * 64 + l) * 8) = v8;
  }
  if (w < 4) {  // kfrag: waves 0-3 -> (jt = w>>1, which = w&1)
    int jt = w >> 1, which = w & 1;
    int pxl = jt * 32 + il;
    bf16x8 k8;
    #pragma unroll
    for (int r = 0; r < 8; ++r) {
      float kv = klds[pxl][r];
      __bf16 hi = (__bf16)kv;
      if (which == 0) {
        k8[r] = hi;                                 // A1: khi in both halves
      } else {
        __bf16 lo = (__bf16)(kv - (float)hi);
        k8[r] = (hA == 0) ? lo : (__bf16)0.f;       // A2: klo | 0
      }
    }
    int jtg = (blk & 63) * 2 + jt;
    *(bf16x8*)(kfrag + ((((size_t)b * 128 + jtg) * 2 + which) * 64 + l) * 8) = k8;
  } else if (w < 6) {  // qfrag: waves 4-5 -> it = w-4 (two 32-i tiles per block)
    int it = w - 4;
    int pxl = it * 32 + il;
    bf16x8 q8;
    #pragma unroll
    for (int r = 0; r < 8; ++r) {
      float qv = qlds[pxl][r];
      __bf16 hi = (__bf16)qv;
      __bf16 lo = (__bf16)(qv - (float)hi);
      q8[r] = (hA == 0) ? hi : lo;
    }
    int itg = (blk & 63) * 2 + it;
    *(bf16x8*)(qfrag + (((size_t)b * 128 + itg) * 64 + l) * 8) = q8;
  }
}

// attn: 256 blocks x 512 thr. Block = batch (blk&7, XCD affinity) x 128 i-rows.
// Each wave: ALL 128 i-rows (4 x 32i tiles, acc = 8 x f32x16 = 128 AGPR) over
// a 16-jt j-slice. Frag reads amortized over 128 rows -> 196 MB total L2/L3
// traffic (vs 393 MB in the 16x16 scheme). Energy: 2 MFMAs. exp results feed
// PV B-operand directly (jperm matches). 8-way j-partials combined in LDS.
// ROUND-8 FIX: the softmax denominator must be per-i-row; round 7 applied the
// even row's 1/l to the odd row too (error ~ denom ratio ~ e^15 = observed
// 3.7e6 absmax). inv_a (i=myi) and inv_b (i=myi+1) now separate.
__global__ __launch_bounds__(512, 2) void attn_kernel(
    const char* __restrict__ ws, const float* __restrict__ value,
    float* __restrict__ out) {
  __shared__ float lds_e[8 * 1028];     // [w][lane][reg], stride 1028
  __shared__ float lsum_lds[32 * 33];   // [(it*8+w)][i], stride 33 bank-clean
  const __bf16* qfrag = (const __bf16*)(ws + QF_OFF);
  const __bf16* kfrag = (const __bf16*)(ws + KF_OFF);
  const __bf16* vfrag = (const __bf16*)(ws + VF_OFF);
  int tid = threadIdx.x;
  int w = tid >> 6, lane = tid & 63;
  int blk = blockIdx.x;            // 256 blocks
  int b = blk & 7;                 // XCD affinity
  int ig = blk >> 3;               // 0..31
  int i0 = ig << 7;                // 128 i-rows per block
  int itg0 = ig * 4;

  bf16x8 qf[4];
  #pragma unroll
  for (int it = 0; it < 4; ++it)
    qf[it] = *(const bf16x8*)(qfrag + (((size_t)b * 128 + itg0 + it) * 64 + lane) * 8);

  f32x16 acc[4][2];
  #pragma unroll
  for (int it = 0; it < 4; ++it)
    #pragma unroll
    for (int ct = 0; ct < 2; ++ct)
      #pragma unroll
      for (int r = 0; r < 16; ++r) acc[it][ct][r] = 0.f;
  float lsum[4] = {0.f, 0.f, 0.f, 0.f};

  const __bf16* kb = kfrag + (((size_t)b * 128 + w * 16) * 2 * 64 + lane) * 8;
  const __bf16* vb = vfrag + (((size_t)b * 128 + w * 16) * 4 * 64 + lane) * 8;
  f32x16 Z = {0.f,0.f,0.f,0.f,0.f,0.f,0.f,0.f,0.f,0.f,0.f,0.f,0.f,0.f,0.f,0.f};

  #pragma unroll 1
  for (int jtl = 0; jtl < 16; ++jtl) {
    bf16x8 kA1 = *(const bf16x8*)(kb);
    bf16x8 kA2 = *(const bf16x8*)(kb + 512);
    bf16x8 vf00 = *(const bf16x8*)(vb);          // ct0 jh0
    bf16x8 vf01 = *(const bf16x8*)(vb + 512);    // ct0 jh1
    bf16x8 vf10 = *(const bf16x8*)(vb + 1024);   // ct1 jh0
    bf16x8 vf11 = *(const bf16x8*)(vb + 1536);   // ct1 jh1
    #pragma unroll
    for (int it = 0; it < 4; ++it) {
      f32x16 e = __builtin_amdgcn_mfma_f32_32x32x16_bf16(kA1, qf[it], Z, 0, 0, 0);
      e = __builtin_amdgcn_mfma_f32_32x32x16_bf16(kA2, qf[it], e, 0, 0, 0);
      bf16x8 p1, p2;
      float ls = 0.f;
      #pragma unroll
      for (int g = 0; g < 8; ++g) {
        float p = EXP2F(e[g]);     ls += p; p1[g] = (__bf16)p;
      }
      #pragma unroll
      for (int g = 0; g < 8; ++g) {
        float p = EXP2F(e[8 + g]); ls += p; p2[g] = (__bf16)p;
      }
      lsum[it] += ls;
      acc[it][0] = __builtin_amdgcn_mfma_f32_32x32x16_bf16(vf00, p1, acc[it][0], 0, 0, 0);
      acc[it][0] = __builtin_amdgcn_mfma_f32_32x32x16_bf16(vf01, p2, acc[it][0], 0, 0, 0);
      acc[it][1] = __builtin_amdgcn_mfma_f32_32x32x16_bf16(vf10, p1, acc[it][1], 0, 0, 0);
      acc[it][1] = __builtin_amdgcn_mfma_f32_32x32x16_bf16(vf11, p2, acc[it][1], 0, 0, 0);
    }
    kb += 1024;   // 2 frags * 512 bf16
    vb += 2048;   // 4 frags * 512 bf16
  }

  // lane (i=lane&31, hl) holds exp-sums over its j-half; xor-32 completes rows
  #pragma unroll
  for (int it = 0; it < 4; ++it) {
    lsum[it] += __shfl_xor(lsum[it], 32, 64);
    if (lane < 32) lsum_lds[(it * 8 + w) * 33 + lane] = lsum[it];
  }

  // epilogue: element e = 2*tid enumerates (c, i) as e = myc*32 + myi;
  // thread handles (myc, myi) and (myc, myi+1). myi is even.
  int myi = (2 * tid) & 31;
  int myc = (2 * tid) >> 5;          // 0..31
  int src_lane = myi + 32 * ((myc >> 2) & 1);
  int src_reg  = (myc & 3) + 4 * (myc >> 3);
  float inv_a[4], inv_b[4];          // per-row denominators: i=myi, i=myi+1

  #pragma unroll
  for (int p = 0; p < 8; ++p) {
    int it = p >> 1, ct = p & 1;
    if (p) __syncthreads();          // protect lds_e before overwrite
    #pragma unroll
    for (int r4 = 0; r4 < 4; ++r4) {
      *(float4*)(lds_e + w * 1028 + lane * 16 + r4 * 4) =
          (float4){acc[it][ct][r4 * 4], acc[it][ct][r4 * 4 + 1],
                   acc[it][ct][r4 * 4 + 2], acc[it][ct][r4 * 4 + 3]};
    }
    __syncthreads();
    if (p == 0) {
      #pragma unroll
      for (int it2 = 0; it2 < 4; ++it2) {
        float lsA = 0.f, lsB = 0.f;
        #pragma unroll
        for (int ww = 0; ww < 8; ++ww) {
          lsA += lsum_lds[(it2 * 8 + ww) * 33 + myi];
          lsB += lsum_lds[(it2 * 8 + ww) * 33 + myi + 1];
        }
        inv_a[it2] = 1.0f / lsA;
        inv_b[it2] = 1.0f / lsB;
      }
    }
    float s0 = 0.f, s1 = 0.f;
    #pragma unroll
    for (int ww = 0; ww < 8; ++ww) {
      s0 += lds_e[ww * 1028 + src_lane * 16 + src_reg];
      s1 += lds_e[ww * 1028 + (src_lane + 1) * 16 + src_reg];
    }
    int c = ct * 32 + myc;
    size_t idx = (((size_t)b * CC + c) * NN) + i0 + it * 32 + myi;
    float2 vv = *(const float2*)(value + idx);
    float2 ov;
    ov.x = s0 * inv_a[it] + vv.x;
    ov.y = s1 * inv_b[it] + vv.y;
    *(float2*)(out + idx) = ov;
  }
}

extern "C" void kernel_launch(void* const* d_in, const int* in_sizes, int n_in,
                              void* d_out, int out_size, void* d_ws, size_t ws_size,
                              hipStream_t stream) {
  const float* query = (const float*)d_in[0];
  const float* value = (const float*)d_in[1];
  const float* Wq = (const float*)d_in[2];
  const float* bq = (const float*)d_in[3];
  const float* Wk = (const float*)d_in[4];
  const float* bk = (const float*)d_in[5];
  const float* Wv = (const float*)d_in[6];
  const float* bv = (const float*)d_in[7];
  float* out = (float*)d_out;

  proj_kernel<<<512, 512, 0, stream>>>(query, value, Wq, bq, Wk, bk, Wv, bv, (char*)d_ws);
  attn_kernel<<<256, 512, 0, stream>>>((const char*)d_ws, value, out);
}

// Round 9
// 139.051 us; speedup vs baseline: 1.0057x; 1.0057x over previous
//
#include <hip/hip_runtime.h>
#include <hip/hip_bf16.h>

typedef __attribute__((ext_vector_type(8))) __bf16 bf16x8;
typedef __attribute__((ext_vector_type(16))) float f32x16;

#if __has_builtin(__builtin_amdgcn_exp2f)
#define EXP2F(x) __builtin_amdgcn_exp2f(x)
#else
#define EXP2F(x) exp2f(x)
#endif

static constexpr int BB = 8, CC = 64, NN = 4096;
// ws layout (bytes): qfrag[1MB] | kfrag[2MB @2MB] | vfrag[4MB @4MB]
static constexpr size_t QF_OFF = 0;
static constexpr size_t KF_OFF = (size_t)2 << 20;
static constexpr size_t VF_OFF = (size_t)4 << 20;

// 32x32x16 fragment arrays (bf16). Operand layouts (gfx950):
//   A[m=lane&31][k=(lane>>5)*8+r]  B[k=(lane>>5)*8+r][n=lane&31]
//   C/D: col(n)=lane&31, row(m)=(reg&3)+8*(reg>>2)+4*(lane>>5), reg in [0,16)
// qfrag[b][it32(128)][lane][8] : i = it32*32+(lane&31); hB=lane>>5:
//     hB=0 -> qhi[r], hB=1 -> qlo[r]   (q pre-scaled by log2e, +bias)
// kfrag[b][jt(128)][2][lane][8] : j = jt*32 + (lane&31)
//     frag0 (A1): k8[r] = khi[r] (both halves)  -> pairs with qhi|qlo
//     frag1 (A2): hA=0 -> klo[r], hA=1 -> 0     -> pairs with qhi only
//   -> energy = khi*qhi + khi*qlo + klo*qhi  (klo*qlo ~2^-18, dropped)
// vfrag[b][jt(128)][ct(2)][jh(2)][lane][8] : c = ct*32+(lane&31);
//     slot r -> j = jt*32 + jh*16 + 4*(lane>>5) + 8*(r>>2) + (r&3)
//     (j-permutation == energy C/D row order per k-half, so exp() results ARE
//      the PV B-operand: p1 = e-regs 0-7 with vfrag jh=0, p2 = regs 8-15 / jh=1)

// proj: R4 compute core (14 us measured; the R6 LDS-staged variant was 34 us)
// + 32x32 fragment building.
__global__ __launch_bounds__(512) void proj_kernel(
    const float* __restrict__ query, const float* __restrict__ value,
    const float* __restrict__ Wq, const float* __restrict__ bq,
    const float* __restrict__ Wk, const float* __restrict__ bk,
    const float* __restrict__ Wv, const float* __restrict__ bv,
    char* __restrict__ ws) {
  __shared__ __bf16 vlds[64][72];   // [px][c], padded row
  __shared__ float  qlds[64][9];    // [px][o], log2e-scaled, +bias
  __shared__ float  klds[64][9];
  const float LOG2E = 1.4426950408889634f;
  int t = threadIdx.x;
  int part = __builtin_amdgcn_readfirstlane(t >> 6);   // 0..7, wave-uniform
  int px = t & 63;
  int blk = blockIdx.x;
  int b = blk >> 6;
  int px0 = (blk & 63) << 6;        // 64 pixels per block
  size_t inbase = (size_t)b * CC * NN + px0 + px;

  bool isq = part < 4;              // parts 0-3 -> q rows, 4-7 -> k rows
  int qko = (part & 3) * 2;         // two qk output rows per part
  const float* __restrict__ Wqk = isq ? Wq : Wk;

  float vacc[8];
  #pragma unroll
  for (int o = 0; o < 8; ++o) vacc[o] = bv[part * 8 + o];
  float qk0 = 0.f, qk1 = 0.f;

  // chunked over c: 16 q-loads + 16 v-loads in flight, then FMA burst with
  // scalar (SGPR) weights. Redundant across parts but latency-clean.
  #pragma unroll
  for (int cb = 0; cb < 4; ++cb) {
    float xq[16], xv[16];
    #pragma unroll
    for (int cc = 0; cc < 16; ++cc) {
      int c = cb * 16 + cc;
      xq[cc] = query[inbase + (size_t)c * NN];
      xv[cc] = value[inbase + (size_t)c * NN];
    }
    #pragma unroll
    for (int cc = 0; cc < 16; ++cc) {
      int c = cb * 16 + cc;
      qk0 += Wqk[qko * 64 + c] * xq[cc];
      qk1 += Wqk[(qko + 1) * 64 + c] * xq[cc];
      #pragma unroll
      for (int o = 0; o < 8; ++o) vacc[o] += Wv[(part * 8 + o) * 64 + c] * xv[cc];
    }
  }

  #pragma unroll
  for (int o = 0; o < 8; ++o) vlds[px][part * 8 + o] = (__bf16)vacc[o];
  if (isq) {
    qlds[px][qko]     = (qk0 + bq[qko]) * LOG2E;
    qlds[px][qko + 1] = (qk1 + bq[qko + 1]) * LOG2E;
  } else {
    klds[px][qko]     = qk0 + bk[qko];
    klds[px][qko + 1] = qk1 + bk[qko + 1];
  }
  __syncthreads();

  // ---- fragment building (32x32 layouts documented above)
  __bf16* qfrag = (__bf16*)(ws + QF_OFF);
  __bf16* kfrag = (__bf16*)(ws + KF_OFF);
  __bf16* vfrag = (__bf16*)(ws + VF_OFF);
  int l = t & 63, il = l & 31, hA = l >> 5;
  int w = t >> 6;

  {  // vfrag: wave w -> (jt = w>>2, ct = (w>>1)&1, jh = w&1); one store each
    int jt = w >> 2, ct = (w >> 1) & 1, jh = w & 1;
    bf16x8 v8;
    #pragma unroll
    for (int r = 0; r < 8; ++r) {
      int jj = jt * 32 + jh * 16 + 4 * hA + 8 * (r >> 2) + (r & 3);
      v8[r] = vlds[jj][ct * 32 + il];
    }
    int jtg = (blk & 63) * 2 + jt;
    *(bf16x8*)(vfrag + (((((size_t)b * 128 + jtg) * 2 + ct) * 2 + jh) * 64 + l) * 8) = v8;
  }
  if (w < 4) {  // kfrag: waves 0-3 -> (jt = w>>1, which = w&1)
    int jt = w >> 1, which = w & 1;
    int pxl = jt * 32 + il;
    bf16x8 k8;
    #pragma unroll
    for (int r = 0; r < 8; ++r) {
      float kv = klds[pxl][r];
      __bf16 hi = (__bf16)kv;
      if (which == 0) {
        k8[r] = hi;                                 // A1: khi in both halves
      } else {
        __bf16 lo = (__bf16)(kv - (float)hi);
        k8[r] = (hA == 0) ? lo : (__bf16)0.f;       // A2: klo | 0
      }
    }
    int jtg = (blk & 63) * 2 + jt;
    *(bf16x8*)(kfrag + ((((size_t)b * 128 + jtg) * 2 + which) * 64 + l) * 8) = k8;
  } else if (w < 6) {  // qfrag: waves 4-5 -> it = w-4 (two 32-i tiles per block)
    int it = w - 4;
    int pxl = it * 32 + il;
    bf16x8 q8;
    #pragma unroll
    for (int r = 0; r < 8; ++r) {
      float qv = qlds[pxl][r];
      __bf16 hi = (__bf16)qv;
      __bf16 lo = (__bf16)(qv - (float)hi);
      q8[r] = (hA == 0) ? hi : lo;
    }
    int itg = (blk & 63) * 2 + it;
    *(bf16x8*)(qfrag + (((size_t)b * 128 + itg) * 64 + l) * 8) = q8;
  }
}

// attn: 256 blocks x 512 thr. Block = batch (blk&7) x 128 i-rows. Each wave:
// all 128 i-rows (acc = 8 x f32x16 = 128 AGPR) over a 16-jt j-slice.
// ROUND-9: epilogue rebuilt conflict-free. lds_e is lane-major with a
// 132-float lane stride: bank = lane*4+..., so 8 lanes span all 32 banks
// (minimal aliasing, same as contiguous b128). Cross-wave sums are b128
// reads; reg-quad rq -> 4 consecutive c-rows -> coalesced global stores.
// R8's lane*16 layout put all even lanes in one bank: 9.4M conflict cycles.
// Main loop gains an even/odd register prefetch double-buffer.
__global__ __launch_bounds__(512, 2) void attn_kernel(
    const char* __restrict__ ws, const float* __restrict__ value,
    float* __restrict__ out) {
  __shared__ float lds_e[64 * 132];     // [lane][w][16], lane stride 132
  __shared__ float lsum_lds[32 * 33];   // [(it*8+w)][i], stride 33 bank-clean
  const __bf16* qfrag = (const __bf16*)(ws + QF_OFF);
  const __bf16* kfrag = (const __bf16*)(ws + KF_OFF);
  const __bf16* vfrag = (const __bf16*)(ws + VF_OFF);
  int tid = threadIdx.x;
  int w = tid >> 6, lane = tid & 63;
  int blk = blockIdx.x;            // 256 blocks
  int b = blk & 7;                 // XCD affinity
  int ig = blk >> 3;               // 0..31
  int i0 = ig << 7;                // 128 i-rows per block
  int itg0 = ig * 4;

  bf16x8 qf[4];
  #pragma unroll
  for (int it = 0; it < 4; ++it)
    qf[it] = *(const bf16x8*)(qfrag + (((size_t)b * 128 + itg0 + it) * 64 + lane) * 8);

  f32x16 acc[4][2];
  #pragma unroll
  for (int it = 0; it < 4; ++it)
    #pragma unroll
    for (int ct = 0; ct < 2; ++ct)
      #pragma unroll
      for (int r = 0; r < 16; ++r) acc[it][ct][r] = 0.f;
  float lsum[4] = {0.f, 0.f, 0.f, 0.f};

  const __bf16* kb = kfrag + (((size_t)b * 128 + w * 16) * 2 * 64 + lane) * 8;
  const __bf16* vb = vfrag + (((size_t)b * 128 + w * 16) * 4 * 64 + lane) * 8;
  f32x16 Z = {0.f,0.f,0.f,0.f,0.f,0.f,0.f,0.f,0.f,0.f,0.f,0.f,0.f,0.f,0.f,0.f};

  auto compute = [&](bf16x8 kA1, bf16x8 kA2, bf16x8 vf00, bf16x8 vf01,
                     bf16x8 vf10, bf16x8 vf11) {
    #pragma unroll
    for (int it = 0; it < 4; ++it) {
      f32x16 e = __builtin_amdgcn_mfma_f32_32x32x16_bf16(kA1, qf[it], Z, 0, 0, 0);
      e = __builtin_amdgcn_mfma_f32_32x32x16_bf16(kA2, qf[it], e, 0, 0, 0);
      bf16x8 p1, p2;
      float ls = 0.f;
      #pragma unroll
      for (int g = 0; g < 8; ++g) {
        float p = EXP2F(e[g]);     ls += p; p1[g] = (__bf16)p;
      }
      #pragma unroll
      for (int g = 0; g < 8; ++g) {
        float p = EXP2F(e[8 + g]); ls += p; p2[g] = (__bf16)p;
      }
      lsum[it] += ls;
      acc[it][0] = __builtin_amdgcn_mfma_f32_32x32x16_bf16(vf00, p1, acc[it][0], 0, 0, 0);
      acc[it][0] = __builtin_amdgcn_mfma_f32_32x32x16_bf16(vf01, p2, acc[it][0], 0, 0, 0);
      acc[it][1] = __builtin_amdgcn_mfma_f32_32x32x16_bf16(vf10, p1, acc[it][1], 0, 0, 0);
      acc[it][1] = __builtin_amdgcn_mfma_f32_32x32x16_bf16(vf11, p2, acc[it][1], 0, 0, 0);
    }
  };

  // prefetch jtl=0
  bf16x8 kA1a = *(const bf16x8*)(kb);
  bf16x8 kA2a = *(const bf16x8*)(kb + 512);
  bf16x8 v00a = *(const bf16x8*)(vb);
  bf16x8 v01a = *(const bf16x8*)(vb + 512);
  bf16x8 v10a = *(const bf16x8*)(vb + 1024);
  bf16x8 v11a = *(const bf16x8*)(vb + 1536);

  #pragma unroll 1
  for (int jtl = 0; jtl < 8; ++jtl) {
    kb += 1024; vb += 2048;
    bf16x8 kA1b = *(const bf16x8*)(kb);
    bf16x8 kA2b = *(const bf16x8*)(kb + 512);
    bf16x8 v00b = *(const bf16x8*)(vb);
    bf16x8 v01b = *(const bf16x8*)(vb + 512);
    bf16x8 v10b = *(const bf16x8*)(vb + 1024);
    bf16x8 v11b = *(const bf16x8*)(vb + 1536);
    compute(kA1a, kA2a, v00a, v01a, v10a, v11a);
    kb += 1024; vb += 2048;
    // final prefetch overshoots into adjacent ws region - harmless, unused
    kA1a = *(const bf16x8*)(kb);
    kA2a = *(const bf16x8*)(kb + 512);
    v00a = *(const bf16x8*)(vb);
    v01a = *(const bf16x8*)(vb + 512);
    v10a = *(const bf16x8*)(vb + 1024);
    v11a = *(const bf16x8*)(vb + 1536);
    compute(kA1b, kA2b, v00b, v01b, v10b, v11b);
  }

  // lane (i=lane&31, hl) holds exp-sums over its j-half; xor-32 completes rows
  #pragma unroll
  for (int it = 0; it < 4; ++it) {
    lsum[it] += __shfl_xor(lsum[it], 32, 64);
    if (lane < 32) lsum_lds[(it * 8 + w) * 33 + lane] = lsum[it];
  }

  // conflict-free 8-pass epilogue: pass p = (it, ct). All waves write their
  // acc tile to lds_e[lane][w][16]; waves 0-3 (rq = w) sum across the 8
  // wave-slots with b128 reads and store 4 consecutive c-rows to global.
  int rq = w & 3;
  float inv_l[4];
  #pragma unroll
  for (int p = 0; p < 8; ++p) {
    int it = p >> 1, ct = p & 1;
    if (p) __syncthreads();          // readers of pass p-1 done before overwrite
    #pragma unroll
    for (int r4 = 0; r4 < 4; ++r4) {
      *(float4*)(lds_e + lane * 132 + w * 16 + r4 * 4) =
          (float4){acc[it][ct][r4 * 4], acc[it][ct][r4 * 4 + 1],
                   acc[it][ct][r4 * 4 + 2], acc[it][ct][r4 * 4 + 3]};
    }
    __syncthreads();
    if (p == 0 && w < 4) {
      #pragma unroll
      for (int it2 = 0; it2 < 4; ++it2) {
        float ls = 0.f;
        #pragma unroll
        for (int ww = 0; ww < 8; ++ww)
          ls += lsum_lds[(it2 * 8 + ww) * 33 + (lane & 31)];
        inv_l[it2] = 1.0f / ls;
      }
    }
    if (w < 4) {
      float sx = 0.f, sy = 0.f, sz = 0.f, sw2 = 0.f;
      #pragma unroll
      for (int ww = 0; ww < 8; ++ww) {
        float4 v4 = *(const float4*)(lds_e + lane * 132 + ww * 16 + rq * 4);
        sx += v4.x; sy += v4.y; sz += v4.z; sw2 += v4.w;
      }
      int c0 = ct * 32 + 8 * rq + 4 * (lane >> 5);   // rows c0..c0+3
      int i  = i0 + it * 32 + (lane & 31);
      float inv = inv_l[it];
      size_t idx = ((size_t)b * CC + c0) * NN + i;
      out[idx]          = sx  * inv + value[idx];
      out[idx + NN]     = sy  * inv + value[idx + NN];
      out[idx + 2 * NN] = sz  * inv + value[idx + 2 * NN];
      out[idx + 3 * NN] = sw2 * inv + value[idx + 3 * NN];
    }
  }
}

extern "C" void kernel_launch(void* const* d_in, const int* in_sizes, int n_in,
                              void* d_out, int out_size, void* d_ws, size_t ws_size,
                              hipStream_t stream) {
  const float* query = (const float*)d_in[0];
  const float* value = (const float*)d_in[1];
  const float* Wq = (const float*)d_in[2];
  const float* bq = (const float*)d_in[3];
  const float* Wk = (const float*)d_in[4];
  const float* bk = (const float*)d_in[5];
  const float* Wv = (const float*)d_in[6];
  const float* bv = (const float*)d_in[7];
  float* out = (float*)d_out;

  proj_kernel<<<512, 512, 0, stream>>>(query, value, Wq, bq, Wk, bk, Wv, bv, (char*)d_ws);
  attn_kernel<<<256, 512, 0, stream>>>((const char*)d_ws, value, out);
}

// Round 11
// 111.089 us; speedup vs baseline: 1.2589x; 1.2517x over previous
//
#include <hip/hip_runtime.h>
#include <hip/hip_bf16.h>

typedef __attribute__((ext_vector_type(8))) __bf16 bf16x8;
typedef __attribute__((ext_vector_type(4))) float f32x4;
typedef __attribute__((ext_vector_type(16))) float f32x16;

#if __has_builtin(__builtin_amdgcn_exp2f)
#define EXP2F(x) __builtin_amdgcn_exp2f(x)
#else
#define EXP2F(x) exp2f(x)
#endif

static constexpr int BB = 8, CC = 64, NN = 4096;
// ws layout (bytes): qfrag[2MB] | kfrag[2MB @2MB] | vfrag[4MB @4MB]
static constexpr size_t QF_OFF = 0;
static constexpr size_t KF_OFF = (size_t)2 << 20;
static constexpr size_t VF_OFF = (size_t)4 << 20;

// 16x16x32 fragment arrays (bf16) — the R6-measured-best attn layouts:
//  qfrag[b][itile(256)][lane][8] : i = itile*16 + (lane&15); qd=lane>>4
//      sections: qd0=qhi, qd1=qlo, qd2=qhi, qd3=qlo (q pre-scaled log2e, +bias)
//  kfrag[b][jt(128)][th(2)][lane][8] : j = jt*32 + th*16 + (lane&15)
//      sections: qd0=khi, qd1=khi, qd2=klo, qd3=klo (+bias)
//  -> energy = (khi+klo)*(qhi+qlo) exact over the bf16 pairs
//  vfrag[b][jt(128)][ct(4)][lane][8] : c = ct*16 + (lane&15); slot r:
//      r<4 -> V[c][jt*32 + 4*qd + r], r>=4 -> V[c][jt*32 + 16 + 4*qd + (r&3)]
//  (jperm matches energy C/D layout: exp() feeds PV B-operand directly)

// proj R11: compute via MFMA (32x32x16). V = Wv·x (A=Wv rows, B=x cols).
// QK exact via row-stacked hi/lo A: rows 0-7 Wq_hi(*log2e), 8-15 Wk_hi,
// 16-23 Wq_lo, 24-31 Wk_lo. D(xhi) gives Whi·xhi AND Wlo·xhi; D(xlo) gives
// Whi·xlo; q[o] = D1[o]+D1[o+16]+D2[o] (rows o, o+16 land in the same lane:
// regs j and 8+j).
// R11 FIX: R10's staging loaded only ONE float4 per 16-px segment (3/4 of
// pixels uninitialized -> absmax 3.66). Now 4x float4 per thread = full tile.
// Staging stride 68 keeps every float4 16B-aligned (66 gave 8B on odd rows).
__global__ __launch_bounds__(256, 2) void proj_kernel(
    const float* __restrict__ query, const float* __restrict__ value,
    const float* __restrict__ Wq, const float* __restrict__ bq,
    const float* __restrict__ Wk, const float* __restrict__ bk,
    const float* __restrict__ Wv, const float* __restrict__ bv,
    char* __restrict__ ws) {
  __shared__ float xqs[64][68];     // query tile [c][px], stride 68 (16B-aligned rows)
  __shared__ float xvs[64][68];     // value tile [c][px]
  __shared__ __bf16 vlds[64][66];   // [px][c] bf16
  __shared__ float  qlds[64][9];    // [px][o], log2e-scaled, +bias
  __shared__ float  klds[64][9];
  const float LOG2E = 1.4426950408889634f;
  int t = threadIdx.x;
  int blk = blockIdx.x;
  int b = blk >> 6;
  int px0 = (blk & 63) << 6;        // 64 px per block

  {  // cooperative input stage: thread t -> channel t>>2, 16-px segment, 4x float4
    int c = t >> 2, seg = (t & 3) << 4;
    size_t gaddr = (size_t)b * CC * NN + (size_t)c * NN + px0 + seg;
    #pragma unroll
    for (int qq = 0; qq < 4; ++qq) {
      *(float4*)&xqs[c][seg + 4 * qq] = *(const float4*)(query + gaddr + 4 * qq);
      *(float4*)&xvs[c][seg + 4 * qq] = *(const float4*)(value + gaddr + 4 * qq);
    }
  }
  __syncthreads();

  int lane = t & 63, m = lane & 31, hA = lane >> 5;
  int w = t >> 6;                   // 4 waves
  int tile = w & 1, role = w >> 1;  // tile: which 32-px half; role: V vs QK
  int pxl = tile * 32 + m;

  f32x16 Z16;
  #pragma unroll
  for (int r = 0; r < 16; ++r) Z16[r] = 0.f;

  if (role == 0) {
    // ---- V-projection: D[c][px] = Wv·value, two 32-c tiles
    bf16x8 A[2][4];
    #pragma unroll
    for (int ct = 0; ct < 2; ++ct)
      #pragma unroll
      for (int kb = 0; kb < 4; ++kb) {
        const float* wb = Wv + (ct * 32 + m) * 64 + kb * 16 + hA * 8;
        #pragma unroll
        for (int r = 0; r < 8; ++r) A[ct][kb][r] = (__bf16)wb[r];
      }
    f32x16 acc0 = Z16, acc1 = Z16;
    #pragma unroll
    for (int kb = 0; kb < 4; ++kb) {
      bf16x8 Bv;
      #pragma unroll
      for (int r = 0; r < 8; ++r) Bv[r] = (__bf16)xvs[kb * 16 + hA * 8 + r][pxl];
      acc0 = __builtin_amdgcn_mfma_f32_32x32x16_bf16(A[0][kb], Bv, acc0, 0, 0, 0);
      acc1 = __builtin_amdgcn_mfma_f32_32x32x16_bf16(A[1][kb], Bv, acc1, 0, 0, 0);
    }
    #pragma unroll
    for (int reg = 0; reg < 16; ++reg) {
      int crow = (reg & 3) + 8 * (reg >> 2) + 4 * hA;
      vlds[pxl][crow]      = (__bf16)(acc0[reg] + bv[crow]);
      vlds[pxl][crow + 32] = (__bf16)(acc1[reg] + bv[crow + 32]);
    }
  } else {
    // ---- QK projection, hi/lo exact (missing term Wlo·xlo ~ 3e-5)
    bf16x8 A[4];
    int r8 = m & 7;
    bool isk = (m >> 3) & 1;                      // rows 8-15 / 24-31 -> Wk
    const float* wrow = (isk ? Wk : Wq) + r8 * 64;
    float scale = isk ? 1.0f : LOG2E;             // fold log2e into Wq
    #pragma unroll
    for (int kb = 0; kb < 4; ++kb) {
      #pragma unroll
      for (int r = 0; r < 8; ++r) {
        float v = wrow[kb * 16 + hA * 8 + r] * scale;
        __bf16 hi = (__bf16)v;
        A[kb][r] = (m < 16) ? hi : (__bf16)(v - (float)hi);
      }
    }
    f32x16 accH = Z16, accL = Z16;
    #pragma unroll
    for (int kb = 0; kb < 4; ++kb) {
      bf16x8 Bh, Bl;
      #pragma unroll
      for (int r = 0; r < 8; ++r) {
        float x = xqs[kb * 16 + hA * 8 + r][pxl];
        __bf16 h = (__bf16)x;
        Bh[r] = h;
        Bl[r] = (__bf16)(x - (float)h);
      }
      accH = __builtin_amdgcn_mfma_f32_32x32x16_bf16(A[kb], Bh, accH, 0, 0, 0);
      accL = __builtin_amdgcn_mfma_f32_32x32x16_bf16(A[kb], Bl, accL, 0, 0, 0);
    }
    // rows o and o+16 sit in the same lane: regs j and 8+j
    #pragma unroll
    for (int j = 0; j < 4; ++j) {
      int o = 4 * hA + j;
      qlds[pxl][o] = accH[j] + accH[8 + j] + accL[j] + bq[o] * LOG2E;
      klds[pxl][o] = accH[4 + j] + accH[12 + j] + accL[4 + j] + bk[o];
    }
  }
  __syncthreads();

  // ---- fragment building (16x16 layouts; 4-wave split)
  __bf16* qfrag = (__bf16*)(ws + QF_OFF);
  __bf16* kfrag = (__bf16*)(ws + KF_OFF);
  __bf16* vfrag = (__bf16*)(ws + VF_OFF);
  int l = lane, cp = l & 15, qd = l >> 4;

  #pragma unroll
  for (int ci = 0; ci < 2; ++ci) {  // vfrag: wave w -> jt = w>>1, ct = 2*(w&1)+ci
    int jt = w >> 1, ct = (w & 1) * 2 + ci;
    bf16x8 v8;
    #pragma unroll
    for (int r = 0; r < 8; ++r) {
      int jj = (r < 4) ? (4 * qd + r) : (16 + 4 * qd + (r & 3));
      v8[r] = vlds[jt * 32 + jj][ct * 16 + cp];
    }
    int jtg = (blk & 63) * 2 + jt;
    *(bf16x8*)(vfrag + ((((size_t)b * 128 + jtg) * 4 + ct) * 64 + l) * 8) = v8;
  }
  {  // kfrag: jt = w>>1, th = w&1
    int jt = w >> 1, th = w & 1;
    int pxk = jt * 32 + th * 16 + cp;
    bf16x8 k8;
    #pragma unroll
    for (int r = 0; r < 8; ++r) {
      float kv = klds[pxk][r];
      __bf16 hi = (__bf16)kv;
      __bf16 lo = (__bf16)(kv - (float)hi);
      k8[r] = (qd < 2) ? hi : lo;
    }
    int jtg = (blk & 63) * 2 + jt;
    *(bf16x8*)(kfrag + ((((size_t)b * 128 + jtg) * 2 + th) * 64 + l) * 8) = k8;
  }
  {  // qfrag: it = w
    int il = w * 16 + cp;
    bf16x8 q8;
    #pragma unroll
    for (int r = 0; r < 8; ++r) {
      float qv = qlds[il][r];
      __bf16 hi = (__bf16)qv;
      __bf16 lo = (__bf16)(qv - (float)hi);
      q8[r] = ((qd & 1) == 0) ? hi : lo;
    }
    int itg = (blk & 63) * 4 + w;
    *(bf16x8*)(qfrag + (((size_t)b * 256 + itg) * 64 + l) * 8) = q8;
  }
}

// attn: the R6-measured-best structure (~34 us). 64 i-rows/block, 4 waves
// each take a j-quarter, acc[4][4] (64 AGPR, no spill at (256,2)),
// even/odd register prefetch, XCD-batch affinity b = blk&7.
__global__ __launch_bounds__(256, 2) void attn_kernel(
    const char* __restrict__ ws, const float* __restrict__ value,
    float* __restrict__ out) {
  __shared__ float lds_acc[32 * 4 * 64];  // [elem(32)][wave(4)][lane] 32KB
  __shared__ float lds_l[16 * 64];        // [(it*4+w)][lane]
  const __bf16* qfrag = (const __bf16*)(ws + QF_OFF);
  const __bf16* kfrag = (const __bf16*)(ws + KF_OFF);
  const __bf16* vfrag = (const __bf16*)(ws + VF_OFF);
  int tid = threadIdx.x;
  int w = tid >> 6, lane = tid & 63;
  int blk = blockIdx.x;            // 512 blocks
  int b = blk & 7;                 // XCD affinity
  int slot = blk >> 3;             // 0..63
  int i0 = slot << 6;
  int itg0 = slot * 4;

  bf16x8 qf[4];
  #pragma unroll
  for (int it = 0; it < 4; ++it)
    qf[it] = *(const bf16x8*)(qfrag + (((size_t)b * 256 + itg0 + it) * 64 + lane) * 8);

  f32x4 acc[4][4];
  #pragma unroll
  for (int ct = 0; ct < 4; ++ct)
    #pragma unroll
    for (int it = 0; it < 4; ++it) acc[ct][it] = (f32x4){0.f, 0.f, 0.f, 0.f};
  float lsum[4] = {0.f, 0.f, 0.f, 0.f};

  const __bf16* kb = kfrag + (((size_t)b * 128 + w * 32) * 2 * 64 + lane) * 8;
  const __bf16* vb = vfrag + (((size_t)b * 128 + w * 32) * 4 * 64 + lane) * 8;

  auto compute = [&](bf16x8 kf0, bf16x8 kf1, bf16x8 vf0, bf16x8 vf1,
                     bf16x8 vf2, bf16x8 vf3) {
    const f32x4 z = (f32x4){0.f, 0.f, 0.f, 0.f};
    #pragma unroll
    for (int it = 0; it < 4; ++it) {
      f32x4 e0 = __builtin_amdgcn_mfma_f32_16x16x32_bf16(kf0, qf[it], z, 0, 0, 0);
      f32x4 e1 = __builtin_amdgcn_mfma_f32_16x16x32_bf16(kf1, qf[it], z, 0, 0, 0);
      bf16x8 pf;
      #pragma unroll
      for (int g = 0; g < 4; ++g) {
        float p0 = EXP2F(e0[g]); lsum[it] += p0; pf[g] = (__bf16)p0;
        float p1 = EXP2F(e1[g]); lsum[it] += p1; pf[4 + g] = (__bf16)p1;
      }
      acc[0][it] = __builtin_amdgcn_mfma_f32_16x16x32_bf16(vf0, pf, acc[0][it], 0, 0, 0);
      acc[1][it] = __builtin_amdgcn_mfma_f32_16x16x32_bf16(vf1, pf, acc[1][it], 0, 0, 0);
      acc[2][it] = __builtin_amdgcn_mfma_f32_16x16x32_bf16(vf2, pf, acc[2][it], 0, 0, 0);
      acc[3][it] = __builtin_amdgcn_mfma_f32_16x16x32_bf16(vf3, pf, acc[3][it], 0, 0, 0);
    }
  };

  // prefetch itx=0
  bf16x8 k0a = *(const bf16x8*)(kb);
  bf16x8 k1a = *(const bf16x8*)(kb + 512);
  bf16x8 v0a = *(const bf16x8*)(vb);
  bf16x8 v1a = *(const bf16x8*)(vb + 512);
  bf16x8 v2a = *(const bf16x8*)(vb + 1024);
  bf16x8 v3a = *(const bf16x8*)(vb + 1536);

  #pragma unroll 1
  for (int itx = 0; itx < 16; ++itx) {
    kb += 1024; vb += 2048;
    bf16x8 k0b = *(const bf16x8*)(kb);
    bf16x8 k1b = *(const bf16x8*)(kb + 512);
    bf16x8 v0b = *(const bf16x8*)(vb);
    bf16x8 v1b = *(const bf16x8*)(vb + 512);
    bf16x8 v2b = *(const bf16x8*)(vb + 1024);
    bf16x8 v3b = *(const bf16x8*)(vb + 1536);
    compute(k0a, k1a, v0a, v1a, v2a, v3a);
    kb += 1024; vb += 2048;
    // last prefetch overshoots into adjacent ws region - harmless, unused
    k0a = *(const bf16x8*)(kb);
    k1a = *(const bf16x8*)(kb + 512);
    v0a = *(const bf16x8*)(vb);
    v1a = *(const bf16x8*)(vb + 512);
    v2a = *(const bf16x8*)(vb + 1024);
    v3a = *(const bf16x8*)(vb + 1536);
    compute(k0b, k1b, v0b, v1b, v2b, v3b);
  }

  #pragma unroll
  for (int it = 0; it < 4; ++it) {
    lsum[it] += __shfl_xor(lsum[it], 16, 64);
    lsum[it] += __shfl_xor(lsum[it], 32, 64);
    lds_l[(it * 4 + w) * 64 + lane] = lsum[it];
  }

  int ect = tid >> 6, l = tid & 63;
  #pragma unroll
  for (int p = 0; p < 2; ++p) {
    if (p) __syncthreads();   // protect lds_acc from overwrite before reads done
    #pragma unroll
    for (int ct = 0; ct < 4; ++ct)
      #pragma unroll
      for (int itl = 0; itl < 2; ++itl)
        #pragma unroll
        for (int r = 0; r < 4; ++r) {
          int e = ct * 8 + itl * 4 + r;
          lds_acc[(e * 4 + w) * 64 + lane] = acc[ct][2 * p + itl][r];
        }
    __syncthreads();
    #pragma unroll
    for (int itl = 0; itl < 2; ++itl) {
      int it = 2 * p + itl;
      float ls = 0.f;
      #pragma unroll
      for (int ww = 0; ww < 4; ++ww) ls += lds_l[(it * 4 + ww) * 64 + (l & 15)];
      float inv = 1.0f / ls;
      int n = i0 + it * 16 + (l & 15);
      #pragma unroll
      for (int r = 0; r < 4; ++r) {
        int e = ect * 8 + itl * 4 + r;
        float s = 0.f;
        #pragma unroll
        for (int ww = 0; ww < 4; ++ww) s += lds_acc[(e * 4 + ww) * 64 + l];
        int c = ect * 16 + (l >> 4) * 4 + r;
        size_t idx = ((size_t)b * CC + c) * NN + n;
        out[idx] = s * inv + value[idx];
      }
    }
  }
}

extern "C" void kernel_launch(void* const* d_in, const int* in_sizes, int n_in,
                              void* d_out, int out_size, void* d_ws, size_t ws_size,
                              hipStream_t stream) {
  const float* query = (const float*)d_in[0];
  const float* value = (const float*)d_in[1];
  const float* Wq = (const float*)d_in[2];
  const float* bq = (const float*)d_in[3];
  const float* Wk = (const float*)d_in[4];
  const float* bk = (const float*)d_in[5];
  const float* Wv = (const float*)d_in[6];
  const float* bv = (const float*)d_in[7];
  float* out = (float*)d_out;

  proj_kernel<<<512, 256, 0, stream>>>(query, value, Wq, bq, Wk, bk, Wv, bv, (char*)d_ws);
  attn_kernel<<<512, 256, 0, stream>>>((const char*)d_ws, value, out);
}